// Round 1
// baseline (48.806 us; speedup 1.0000x reference)
//
#include <hip/hip_runtime.h>

// Problem constants (from reference):
//   B=16, H=32, W=32, C=16, KH=KW=3, F=32, HO=WO=30, K=144 (+1 bias row)
// out[b,k,ho,wo,f]:
//   k < 144: k = kh*48 + kw*16 + c  ->  x[b, ho+kh, wo+kw, c] * w[k,f]
//   k == 144:                            1.0 * w[144,f]
// Output: (16,145,30,30,32) fp32, contiguous, 267 MB -> write-BW bound.

#define BB   16
#define HH   32
#define WW   32
#define CC   16
#define FF   32
#define KP1  145
#define HOO  30
#define WOO  30
#define LL   900   // HO*WO

__global__ __launch_bounds__(256) void vinput_conv_kernel(
    const float* __restrict__ x,      // (B,H,W,C)
    const float* __restrict__ w,      // (K+1,1,F) -> w[k*F + f]
    float* __restrict__ out,          // (B,K+1,HO,WO,F)
    int total4)                       // total float4 stores
{
    const int stride = gridDim.x * blockDim.x;
    for (int u = blockIdx.x * blockDim.x + threadIdx.x; u < total4; u += stride) {
        // u indexes float4s: layout ((b*145 + k)*900 + l)*8 + f4
        const int f4   = u & 7;       // F/4 = 8 (pow2)
        const int rest = u >> 3;      // (b*145 + k)*900 + l
        const int l    = rest % LL;   // magic-mul division by constants
        const int bk   = rest / LL;
        const int k    = bk % KP1;
        const int b    = bk / KP1;

        float g;
        if (k == 144) {
            g = 1.0f;                 // bias row (wave-uniform branch: k constant per 8-lane group,
                                      // and almost always per wave)
        } else {
            const int kh = k / 48;            // k = kh*48 + kw*16 + c
            const int r  = k - kh * 48;
            const int kw = r >> 4;
            const int c  = r & 15;
            const int ho = l / 30;
            const int wo = l - ho * 30;
            g = x[(((b * HH) + (ho + kh)) * WW + (wo + kw)) * CC + c];
        }

        const float4 wv = *reinterpret_cast<const float4*>(w + k * FF + f4 * 4);
        float4 o;
        o.x = g * wv.x;
        o.y = g * wv.y;
        o.z = g * wv.z;
        o.w = g * wv.w;
        reinterpret_cast<float4*>(out)[u] = o;
    }
}

extern "C" void kernel_launch(void* const* d_in, const int* in_sizes, int n_in,
                              void* d_out, int out_size, void* d_ws, size_t ws_size,
                              hipStream_t stream) {
    const float* x = (const float*)d_in[0];            // (16,32,32,16) fp32
    const float* w = (const float*)d_in[1];            // (145,1,32) fp32
    float* out = (float*)d_out;                        // (16,145,30,30,32) fp32

    const int total4 = (BB * KP1 * LL * FF) / 4;       // 16,704,000 float4 stores

    const int block = 256;
    const int grid  = 2048;                            // grid-stride; ~8 blocks/CU
    vinput_conv_kernel<<<grid, block, 0, stream>>>(x, w, out, total4);
}